// Round 12
// baseline (247.177 us; speedup 1.0000x reference)
//
#include <hip/hip_runtime.h>
#include <math.h>

// Channelatt: x(32,256,56,56) f32 -> x * sigmoid(gate(n,c))
// DIAGNOSTIC: k3 repeated 6x, k4 repeated 16x (both idempotent) to surface
// their counters in rocprof top-5. Ledger: k1<=7, k5=31 (measured),
// k2+k3+k4+gaps ~45-50 -> this round splits that block.

#define N_ 32
#define C_ 256
#define H_ 56
#define W_ 56
#define S_ 3136   // H_*W_
#define Q_ 784    // S_/4 (float4 units)
#define LN_EPS 1e-5f

#define NCH 16    // c-chunks in pass 1
#define CPC 16    // channels per chunk (NCH*CPC == C_)
#define SQ  4     // s-chunks in pass 1
#define QCH 196   // f4 per s-chunk (Q_/SQ)
#define K3REPS 6
#define K4REPS 16

using f4 = __attribute__((ext_vector_type(4))) float;

__device__ __forceinline__ float wave_sum(float v) {
  #pragma unroll
  for (int o = 32; o > 0; o >>= 1) v += __shfl_xor(v, o);
  return v;
}
__device__ __forceinline__ float wave_max(float v) {
  #pragma unroll
  for (int o = 32; o > 0; o >>= 1) v = fmaxf(v, __shfl_xor(v, o));
  return v;
}
__device__ __forceinline__ float block_sum(float v, float* red) {
  int lane = threadIdx.x & 63, wid = threadIdx.x >> 6;
  float w = wave_sum(v);
  __syncthreads();
  if (lane == 0) red[wid] = w;
  __syncthreads();
  return red[0] + red[1] + red[2] + red[3];
}
__device__ __forceinline__ float dot4(f4 a, f4 b) {
  return a.x * b.x + a.y * b.y + a.z * b.z + a.w * b.w;
}
__device__ __forceinline__ float max4(f4 a) {
  return fmaxf(fmaxf(a.x, a.y), fmaxf(a.z, a.w));
}

// K1: partial logits. Block = (c-chunk, n, s-chunk) = 2048 blocks.
__global__ __launch_bounds__(256)
void k_logits(const float* __restrict__ x, const float* __restrict__ gc_w,
              float* __restrict__ lpart) {
  int ch = blockIdx.x, n = blockIdx.y, sq = blockIdx.z;
  int tid = threadIdx.x;
  int c0 = ch * CPC;
  if (tid >= QCH) return;
  int q = sq * QCH + tid;
  const f4* xb = (const f4*)x + ((size_t)n * C_ + c0) * Q_ + q;
  f4 A = {0,0,0,0};
  #pragma unroll
  for (int c = 0; c < CPC; ++c) A += gc_w[c0 + c] * xb[(size_t)c * Q_];
  ((f4*)lpart)[((size_t)n * NCH + ch) * Q_ + q] = A;
}

// K2: fold 16 partials -> softmax over s per n. One block per n, float4.
__global__ void k_softmax(const float* __restrict__ lpart, float* __restrict__ attn) {
  int n = blockIdx.x, tid = threadIdx.x;
  __shared__ float red[4];
  const f4* lp = (const f4*)lpart + (size_t)n * NCH * Q_;
  f4 v[4];
  float m = -INFINITY;
  #pragma unroll
  for (int k = 0; k < 3; ++k) {
    int q = tid + k * 256;
    f4 acc = {0,0,0,0};
    #pragma unroll
    for (int ch = 0; ch < NCH; ++ch) acc += lp[(size_t)ch * Q_ + q];
    v[k] = acc;
    m = fmaxf(m, max4(acc));
  }
  if (tid < 16) {
    f4 acc = {0,0,0,0};
    #pragma unroll
    for (int ch = 0; ch < NCH; ++ch) acc += lp[(size_t)ch * Q_ + 768 + tid];
    v[3] = acc;
    m = fmaxf(m, max4(acc));
  } else {
    v[3] = f4{-INFINITY, -INFINITY, -INFINITY, -INFINITY};
  }
  float wm = wave_max(m);
  int lane = tid & 63, wid = tid >> 6;
  if (lane == 0) red[wid] = wm;
  __syncthreads();
  m = fmaxf(fmaxf(red[0], red[1]), fmaxf(red[2], red[3]));
  float z = 0.f;
  #pragma unroll
  for (int k = 0; k < 4; ++k) {
    v[k].x = expf(v[k].x - m); v[k].y = expf(v[k].y - m);
    v[k].z = expf(v[k].z - m); v[k].w = expf(v[k].w - m);
    z += v[k].x + v[k].y + v[k].z + v[k].w;   // exp(-inf)=0 for tail lanes
  }
  z = block_sum(z, red);
  float inv = 1.f / z;
  f4* ap = (f4*)attn + (size_t)n * Q_;
  #pragma unroll
  for (int k = 0; k < 3; ++k) ap[tid + k * 256] = v[k] * inv;
  if (tid < 16) ap[768 + tid] = v[3] * inv;
}

// K3 x6: per (n,c): x_g, x_max, x_dct. Block per (c,n) = 8192.
__global__ void k_stats_x6(const float* __restrict__ x, const float* __restrict__ attn,
                           float* __restrict__ xg, float* __restrict__ xmax,
                           float* __restrict__ xdct) {
  int c = blockIdx.x, n = blockIdx.y, tid = threadIdx.x;
  __shared__ float bh[H_];
  __shared__ f4 bw4[14];
  __shared__ float red[3][4];
  int grp = c >> 6;
  int u = grp >> 1, vv = grp & 1;
  const float invs = 0.13363062f;   // 1/sqrt(56)
  const float sq2  = 1.41421356f;
  if (tid < H_) {
    float b = cosf((float)M_PI * u * (tid + 0.5f) / H_) * invs;
    bh[tid] = u ? b * sq2 : b;
  } else if (tid >= 64 && tid < 64 + 14) {
    int j = tid - 64;
    f4 b;
    #pragma unroll
    for (int e = 0; e < 4; ++e) {
      float t = cosf((float)M_PI * vv * (4 * j + e + 0.5f) / W_) * invs;
      ((float*)&b)[e] = vv ? t * sq2 : t;
    }
    bw4[j] = b;
  }
  __syncthreads();
  const f4* xp = (const f4*)(x + ((size_t)n * C_ + c) * S_);
  const f4* ap = (const f4*)(attn + (size_t)n * S_);
  int lane = tid & 63, wid = tid >> 6;
  for (int rep = 0; rep < K3REPS; ++rep) {
    __syncthreads();   // protect red across reps
    float g = 0.f, d = 0.f, mx = -INFINITY;
    #pragma unroll
    for (int k = 0; k < 3; ++k) {
      int q = tid + k * 256;
      f4 xv = xp[q], av = ap[q];
      g += dot4(xv, av);
      mx = fmaxf(max4(xv), mx);
      int h = q / 14;
      d += bh[h] * dot4(xv, bw4[q - h * 14]);
    }
    if (tid < 16) {
      int q = 768 + tid;
      f4 xv = xp[q], av = ap[q];
      g += dot4(xv, av);
      mx = fmaxf(max4(xv), mx);
      int h = q / 14;
      d += bh[h] * dot4(xv, bw4[q - h * 14]);
    }
    float gs = wave_sum(g), ms = wave_max(mx), ds = wave_sum(d);
    if (lane == 0) { red[0][wid] = gs; red[1][wid] = ms; red[2][wid] = ds; }
    __syncthreads();
    if (tid == 0) {
      xg[n * C_ + c]   = red[0][0] + red[0][1] + red[0][2] + red[0][3];
      xmax[n * C_ + c] = fmaxf(fmaxf(red[1][0], red[1][1]), fmaxf(red[1][2], red[1][3]));
      xdct[n * C_ + c] = red[2][0] + red[2][1] + red[2][2] + red[2][3];
    }
    asm volatile("" ::: "memory");   // forbid cross-rep CSE
  }
}

// K4 x16: per-(n,c) gate math. One block per n, thread = channel.
__global__ void k_gate_x16(const float* __restrict__ xg, const float* __restrict__ xmax,
                           const float* __restrict__ xdct,
                           const float* __restrict__ lc_w, const float* __restrict__ lc_b,
                           const float* __restrict__ lcln_g, const float* __restrict__ lcln_b,
                           const float* __restrict__ tw_w, const float* __restrict__ tw_b,
                           const float* __restrict__ twln_g, const float* __restrict__ twln_b,
                           const float* __restrict__ wdct, const float* __restrict__ wmax,
                           float* __restrict__ gate) {
  int n = blockIdx.x, c = threadIdx.x;
  __shared__ float xs[C_ + 2];
  __shared__ float att_s[C_];
  __shared__ float red[4];
  for (int rep = 0; rep < K4REPS; ++rep) {
    __syncthreads();   // protect shared reuse across reps
    float g  = xg[n * C_ + c];
    float sv = wmax[c] * xmax[n * C_ + c] + wdct[c] * xdct[n * C_ + c];
    xs[c + 1] = sv;
    if (c == 0) { xs[0] = 0.f; xs[C_ + 1] = 0.f; }
    __syncthreads();
    float xl = lc_w[0] * xs[c] + lc_w[1] * xs[c + 1] + lc_w[2] * xs[c + 2] + lc_b[0];
    float t = g + sv + xl;
    float mu  = block_sum(t, red) * (1.f / C_);
    float dv  = t - mu;
    float var = block_sum(dv * dv, red) * (1.f / C_);
    float att = dv * rsqrtf(var + LN_EPS) * lcln_g[c] + lcln_b[c];
    att_s[c] = att;
    __syncthreads();
    float a2 = tw_b[c];
    const f4* wrow = (const f4*)(tw_w + c * C_);
    const f4* arow = (const f4*)att_s;
    #pragma unroll 8
    for (int k = 0; k < C_ / 4; ++k) a2 += dot4(wrow[k], arow[k]);
    float mu2  = block_sum(a2, red) * (1.f / C_);
    float d2   = a2 - mu2;
    float var2 = block_sum(d2 * d2, red) * (1.f / C_);
    float z = d2 * rsqrtf(var2 + LN_EPS) * twln_g[c] + twln_b[c];
    gate[n * C_ + c] = 1.f / (1.f + expf(-z));
    asm volatile("" ::: "memory");   // forbid cross-rep CSE
  }
}

// K5: out = x * gate[n,c], float4 grid-stride, NT stores.
__global__ void k_scale(const float* __restrict__ x, const float* __restrict__ gate,
                        float* __restrict__ out) {
  const f4* x4 = (const f4*)x;
  f4* o4 = (f4*)out;
  const int total = N_ * C_ * Q_;
  for (int i = blockIdx.x * blockDim.x + threadIdx.x; i < total;
       i += gridDim.x * blockDim.x) {
    int nc = i / Q_;
    float gv = gate[nc];
    f4 v = x4[i];
    v *= gv;
    __builtin_nontemporal_store(v, &o4[i]);
  }
}

extern "C" void kernel_launch(void* const* d_in, const int* in_sizes, int n_in,
                              void* d_out, int out_size, void* d_ws, size_t ws_size,
                              hipStream_t stream) {
  const float* x      = (const float*)d_in[0];
  const float* gc_w   = (const float*)d_in[1];
  // d_in[2] = gc_b: softmax shift-invariant, unused
  const float* lc_w   = (const float*)d_in[3];
  const float* lc_b   = (const float*)d_in[4];
  const float* lcln_g = (const float*)d_in[5];
  const float* lcln_b = (const float*)d_in[6];
  const float* tw_w   = (const float*)d_in[7];
  const float* tw_b   = (const float*)d_in[8];
  const float* twln_g = (const float*)d_in[9];
  const float* twln_b = (const float*)d_in[10];
  const float* wdct   = (const float*)d_in[11];
  const float* wmax   = (const float*)d_in[12];
  float* out = (float*)d_out;

  float* ws    = (float*)d_ws;
  float* lpart = ws;                                   // NCH*N*S
  float* attn  = lpart + (size_t)NCH * N_ * S_;        // N*S
  float* xg    = attn + (size_t)N_ * S_;               // N*C
  float* xmax_ = xg + N_ * C_;
  float* xdct_ = xmax_ + N_ * C_;
  float* gate  = xdct_ + N_ * C_;

  hipLaunchKernelGGL(k_logits, dim3(NCH, N_, SQ), dim3(256), 0, stream, x, gc_w, lpart);
  hipLaunchKernelGGL(k_softmax, dim3(N_), dim3(256), 0, stream, lpart, attn);
  hipLaunchKernelGGL(k_stats_x6, dim3(C_, N_), dim3(256), 0, stream, x, attn, xg, xmax_, xdct_);
  hipLaunchKernelGGL(k_gate_x16, dim3(N_), dim3(256), 0, stream,
                     xg, xmax_, xdct_, lc_w, lc_b, lcln_g, lcln_b,
                     tw_w, tw_b, twln_g, twln_b, wdct, wmax, gate);
  hipLaunchKernelGGL(k_scale, dim3(2048), dim3(256), 0, stream, x, gate, out);
}

// Round 13
// 105.985 us; speedup vs baseline: 2.3322x; 2.3322x over previous
//
#include <hip/hip_runtime.h>
#include <math.h>

// Channelatt: x(32,256,56,56) f32 -> x * sigmoid(gate(n,c))
// Budget (measured R10-R12): k1~15-25 (cold HBM), k2~3-5, k3~5.5 (L3-fed),
// k4 was 8.9 (uncoalesced matmul -> fixed here), k5~31 (copy roofline),
// gaps ~10-15. This round: wave-cooperative coalesced matmul in k4.

#define N_ 32
#define C_ 256
#define H_ 56
#define W_ 56
#define S_ 3136   // H_*W_
#define Q_ 784    // S_/4 (float4 units)
#define LN_EPS 1e-5f

#define NCH 16    // c-chunks in pass 1
#define CPC 16    // channels per chunk (NCH*CPC == C_)
#define SQ  4     // s-chunks in pass 1
#define QCH 196   // f4 per s-chunk (Q_/SQ)

using f4 = __attribute__((ext_vector_type(4))) float;

__device__ __forceinline__ float wave_sum(float v) {
  #pragma unroll
  for (int o = 32; o > 0; o >>= 1) v += __shfl_xor(v, o);
  return v;
}
__device__ __forceinline__ float wave_max(float v) {
  #pragma unroll
  for (int o = 32; o > 0; o >>= 1) v = fmaxf(v, __shfl_xor(v, o));
  return v;
}
__device__ __forceinline__ float block_sum(float v, float* red) {
  int lane = threadIdx.x & 63, wid = threadIdx.x >> 6;
  float w = wave_sum(v);
  __syncthreads();
  if (lane == 0) red[wid] = w;
  __syncthreads();
  return red[0] + red[1] + red[2] + red[3];
}
__device__ __forceinline__ float dot4(f4 a, f4 b) {
  return a.x * b.x + a.y * b.y + a.z * b.z + a.w * b.w;
}
__device__ __forceinline__ float max4(f4 a) {
  return fmaxf(fmaxf(a.x, a.y), fmaxf(a.z, a.w));
}

// K1: partial logits. Block = (c-chunk, n, s-chunk) = 2048 blocks.
__global__ __launch_bounds__(256)
void k_logits(const float* __restrict__ x, const float* __restrict__ gc_w,
              float* __restrict__ lpart) {
  int ch = blockIdx.x, n = blockIdx.y, sq = blockIdx.z;
  int tid = threadIdx.x;
  int c0 = ch * CPC;
  if (tid >= QCH) return;
  int q = sq * QCH + tid;
  const f4* xb = (const f4*)x + ((size_t)n * C_ + c0) * Q_ + q;
  f4 A = {0,0,0,0};
  #pragma unroll
  for (int c = 0; c < CPC; ++c) A += gc_w[c0 + c] * xb[(size_t)c * Q_];
  ((f4*)lpart)[((size_t)n * NCH + ch) * Q_ + q] = A;
}

// K2: fold 16 partials -> softmax over s per n. One block per n, float4.
__global__ void k_softmax(const float* __restrict__ lpart, float* __restrict__ attn) {
  int n = blockIdx.x, tid = threadIdx.x;
  __shared__ float red[4];
  const f4* lp = (const f4*)lpart + (size_t)n * NCH * Q_;
  f4 v[4];
  float m = -INFINITY;
  #pragma unroll
  for (int k = 0; k < 3; ++k) {
    int q = tid + k * 256;
    f4 acc = {0,0,0,0};
    #pragma unroll
    for (int ch = 0; ch < NCH; ++ch) acc += lp[(size_t)ch * Q_ + q];
    v[k] = acc;
    m = fmaxf(m, max4(acc));
  }
  if (tid < 16) {
    f4 acc = {0,0,0,0};
    #pragma unroll
    for (int ch = 0; ch < NCH; ++ch) acc += lp[(size_t)ch * Q_ + 768 + tid];
    v[3] = acc;
    m = fmaxf(m, max4(acc));
  } else {
    v[3] = f4{-INFINITY, -INFINITY, -INFINITY, -INFINITY};
  }
  float wm = wave_max(m);
  int lane = tid & 63, wid = tid >> 6;
  if (lane == 0) red[wid] = wm;
  __syncthreads();
  m = fmaxf(fmaxf(red[0], red[1]), fmaxf(red[2], red[3]));
  float z = 0.f;
  #pragma unroll
  for (int k = 0; k < 4; ++k) {
    v[k].x = expf(v[k].x - m); v[k].y = expf(v[k].y - m);
    v[k].z = expf(v[k].z - m); v[k].w = expf(v[k].w - m);
    z += v[k].x + v[k].y + v[k].z + v[k].w;   // exp(-inf)=0 for tail lanes
  }
  z = block_sum(z, red);
  float inv = 1.f / z;
  f4* ap = (f4*)attn + (size_t)n * Q_;
  #pragma unroll
  for (int k = 0; k < 3; ++k) ap[tid + k * 256] = v[k] * inv;
  if (tid < 16) ap[768 + tid] = v[3] * inv;
}

// K3: per (n,c): x_g, x_max, x_dct in one warm x pass. Block per (c,n) = 8192.
__global__ void k_stats(const float* __restrict__ x, const float* __restrict__ attn,
                        float* __restrict__ xg, float* __restrict__ xmax,
                        float* __restrict__ xdct) {
  int c = blockIdx.x, n = blockIdx.y, tid = threadIdx.x;
  __shared__ float bh[H_];
  __shared__ f4 bw4[14];
  __shared__ float red[3][4];
  int grp = c >> 6;
  int u = grp >> 1, vv = grp & 1;
  const float invs = 0.13363062f;   // 1/sqrt(56)
  const float sq2  = 1.41421356f;
  if (tid < H_) {
    float b = cosf((float)M_PI * u * (tid + 0.5f) / H_) * invs;
    bh[tid] = u ? b * sq2 : b;
  } else if (tid >= 64 && tid < 64 + 14) {
    int j = tid - 64;
    f4 b;
    #pragma unroll
    for (int e = 0; e < 4; ++e) {
      float t = cosf((float)M_PI * vv * (4 * j + e + 0.5f) / W_) * invs;
      ((float*)&b)[e] = vv ? t * sq2 : t;
    }
    bw4[j] = b;
  }
  __syncthreads();
  const f4* xp = (const f4*)(x + ((size_t)n * C_ + c) * S_);
  const f4* ap = (const f4*)(attn + (size_t)n * S_);
  float g = 0.f, d = 0.f, mx = -INFINITY;
  #pragma unroll
  for (int k = 0; k < 3; ++k) {
    int q = tid + k * 256;
    f4 xv = xp[q], av = ap[q];
    g += dot4(xv, av);
    mx = fmaxf(max4(xv), mx);
    int h = q / 14;
    d += bh[h] * dot4(xv, bw4[q - h * 14]);
  }
  if (tid < 16) {
    int q = 768 + tid;
    f4 xv = xp[q], av = ap[q];
    g += dot4(xv, av);
    mx = fmaxf(max4(xv), mx);
    int h = q / 14;
    d += bh[h] * dot4(xv, bw4[q - h * 14]);
  }
  float gs = wave_sum(g), ms = wave_max(mx), ds = wave_sum(d);
  int lane = tid & 63, wid = tid >> 6;
  if (lane == 0) { red[0][wid] = gs; red[1][wid] = ms; red[2][wid] = ds; }
  __syncthreads();
  if (tid == 0) {
    xg[n * C_ + c]   = red[0][0] + red[0][1] + red[0][2] + red[0][3];
    xmax[n * C_ + c] = fmaxf(fmaxf(red[1][0], red[1][1]), fmaxf(red[1][2], red[1][3]));
    xdct[n * C_ + c] = red[2][0] + red[2][1] + red[2][2] + red[2][3];
  }
}

// K4: per-(n,c) gate math. One block per n, thread = channel.
// Matmul is WAVE-COOPERATIVE: wave w computes rows w*64..w*64+63; per row all
// 64 lanes issue one coalesced 1KB load of tw_w[row][*], dot with lane-held
// att fragment, 6-shuffle reduce. (R12: per-thread-row dot was 64 scattered
// 16B requests/wave-instr -> 8.9us at 1% VALUBusy.)
__global__ void k_gate(const float* __restrict__ xg, const float* __restrict__ xmax,
                       const float* __restrict__ xdct,
                       const float* __restrict__ lc_w, const float* __restrict__ lc_b,
                       const float* __restrict__ lcln_g, const float* __restrict__ lcln_b,
                       const float* __restrict__ tw_w, const float* __restrict__ tw_b,
                       const float* __restrict__ twln_g, const float* __restrict__ twln_b,
                       const float* __restrict__ wdct, const float* __restrict__ wmax,
                       float* __restrict__ gate) {
  int n = blockIdx.x, c = threadIdx.x;
  int lane = c & 63, wid = c >> 6;
  __shared__ float xs[C_ + 2];
  __shared__ float att_s[C_];
  __shared__ float att2_s[C_];
  __shared__ float red[4];
  float g  = xg[n * C_ + c];
  float sv = wmax[c] * xmax[n * C_ + c] + wdct[c] * xdct[n * C_ + c];
  xs[c + 1] = sv;
  if (c == 0) { xs[0] = 0.f; xs[C_ + 1] = 0.f; }
  __syncthreads();
  float xl = lc_w[0] * xs[c] + lc_w[1] * xs[c + 1] + lc_w[2] * xs[c + 2] + lc_b[0];
  float t = g + sv + xl;
  float mu  = block_sum(t, red) * (1.f / C_);
  float dv  = t - mu;
  float var = block_sum(dv * dv, red) * (1.f / C_);
  float att = dv * rsqrtf(var + LN_EPS) * lcln_g[c] + lcln_b[c];
  att_s[c] = att;
  __syncthreads();
  // wave-cooperative matmul: att2_s[row] = dot(tw_w[row], att_s)
  const f4 av = ((const f4*)att_s)[lane];        // lane's att fragment, reused 64x
  const f4* twr = (const f4*)tw_w;
  #pragma unroll 8
  for (int r = 0; r < 64; ++r) {
    int row = wid * 64 + r;
    float p = dot4(twr[(size_t)row * 64 + lane], av);
    p = wave_sum(p);
    if (lane == 0) att2_s[row] = p;
  }
  __syncthreads();
  float a2 = att2_s[c] + tw_b[c];
  float mu2  = block_sum(a2, red) * (1.f / C_);
  float d2   = a2 - mu2;
  float var2 = block_sum(d2 * d2, red) * (1.f / C_);
  float z = d2 * rsqrtf(var2 + LN_EPS) * twln_g[c] + twln_b[c];
  gate[n * C_ + c] = 1.f / (1.f + expf(-z));
}

// K5: out = x * gate[n,c], float4 grid-stride, NT stores.
__global__ void k_scale(const float* __restrict__ x, const float* __restrict__ gate,
                        float* __restrict__ out) {
  const f4* x4 = (const f4*)x;
  f4* o4 = (f4*)out;
  const int total = N_ * C_ * Q_;
  for (int i = blockIdx.x * blockDim.x + threadIdx.x; i < total;
       i += gridDim.x * blockDim.x) {
    int nc = i / Q_;
    float gv = gate[nc];
    f4 v = x4[i];
    v *= gv;
    __builtin_nontemporal_store(v, &o4[i]);
  }
}

extern "C" void kernel_launch(void* const* d_in, const int* in_sizes, int n_in,
                              void* d_out, int out_size, void* d_ws, size_t ws_size,
                              hipStream_t stream) {
  const float* x      = (const float*)d_in[0];
  const float* gc_w   = (const float*)d_in[1];
  // d_in[2] = gc_b: softmax shift-invariant, unused
  const float* lc_w   = (const float*)d_in[3];
  const float* lc_b   = (const float*)d_in[4];
  const float* lcln_g = (const float*)d_in[5];
  const float* lcln_b = (const float*)d_in[6];
  const float* tw_w   = (const float*)d_in[7];
  const float* tw_b   = (const float*)d_in[8];
  const float* twln_g = (const float*)d_in[9];
  const float* twln_b = (const float*)d_in[10];
  const float* wdct   = (const float*)d_in[11];
  const float* wmax   = (const float*)d_in[12];
  float* out = (float*)d_out;

  float* ws    = (float*)d_ws;
  float* lpart = ws;                                   // NCH*N*S
  float* attn  = lpart + (size_t)NCH * N_ * S_;        // N*S
  float* xg    = attn + (size_t)N_ * S_;               // N*C
  float* xmax_ = xg + N_ * C_;
  float* xdct_ = xmax_ + N_ * C_;
  float* gate  = xdct_ + N_ * C_;

  hipLaunchKernelGGL(k_logits, dim3(NCH, N_, SQ), dim3(256), 0, stream, x, gc_w, lpart);
  hipLaunchKernelGGL(k_softmax, dim3(N_), dim3(256), 0, stream, lpart, attn);
  hipLaunchKernelGGL(k_stats, dim3(C_, N_), dim3(256), 0, stream, x, attn, xg, xmax_, xdct_);
  hipLaunchKernelGGL(k_gate, dim3(N_), dim3(256), 0, stream,
                     xg, xmax_, xdct_, lc_w, lc_b, lcln_g, lcln_b,
                     tw_w, tw_b, twln_g, twln_b, wdct, wmax, gate);
  hipLaunchKernelGGL(k_scale, dim3(2048), dim3(256), 0, stream, x, gate, out);
}

// Round 14
// 82.710 us; speedup vs baseline: 2.9885x; 1.2814x over previous
//
#include <hip/hip_runtime.h>
#include <math.h>

// Channelatt: x(32,256,56,56) f32 -> x * sigmoid(gate(n,c))
// Budget (measured R10-R13): k1~20-25 (cold HBM), k2~4, k3~5.5 (L3-fed),
// k5~31 (copy roofline), gaps~10-15. k4 history: 8.9 (per-thread row,
// uncoalesced, 4 waves/CU) -> 29 (wave-coop serial shuffles, R13 regression)
// -> this: 1024-thr block, 4-thr/row coalesced matmul, 16 waves/CU.

#define N_ 32
#define C_ 256
#define H_ 56
#define W_ 56
#define S_ 3136   // H_*W_
#define Q_ 784    // S_/4 (float4 units)
#define LN_EPS 1e-5f

#define NCH 16    // c-chunks in pass 1
#define CPC 16    // channels per chunk (NCH*CPC == C_)
#define SQ  4     // s-chunks in pass 1
#define QCH 196   // f4 per s-chunk (Q_/SQ)

using f4 = __attribute__((ext_vector_type(4))) float;

__device__ __forceinline__ float wave_sum(float v) {
  #pragma unroll
  for (int o = 32; o > 0; o >>= 1) v += __shfl_xor(v, o);
  return v;
}
__device__ __forceinline__ float wave_max(float v) {
  #pragma unroll
  for (int o = 32; o > 0; o >>= 1) v = fmaxf(v, __shfl_xor(v, o));
  return v;
}
// 256-thread block sum (4 waves)
__device__ __forceinline__ float block_sum(float v, float* red) {
  int lane = threadIdx.x & 63, wid = threadIdx.x >> 6;
  float w = wave_sum(v);
  __syncthreads();
  if (lane == 0) red[wid] = w;
  __syncthreads();
  return red[0] + red[1] + red[2] + red[3];
}
// 1024-thread block sum (16 waves)
__device__ __forceinline__ float block_sum16(float v, float* red) {
  int lane = threadIdx.x & 63, wid = threadIdx.x >> 6;
  float w = wave_sum(v);
  __syncthreads();
  if (lane == 0) red[wid] = w;
  __syncthreads();
  float s = 0.f;
  #pragma unroll
  for (int i = 0; i < 16; ++i) s += red[i];
  return s;
}
__device__ __forceinline__ float dot4(f4 a, f4 b) {
  return a.x * b.x + a.y * b.y + a.z * b.z + a.w * b.w;
}
__device__ __forceinline__ float max4(f4 a) {
  return fmaxf(fmaxf(a.x, a.y), fmaxf(a.z, a.w));
}

// K1: partial logits. Block = (c-chunk, n, s-chunk) = 2048 blocks.
__global__ __launch_bounds__(256)
void k_logits(const float* __restrict__ x, const float* __restrict__ gc_w,
              float* __restrict__ lpart) {
  int ch = blockIdx.x, n = blockIdx.y, sq = blockIdx.z;
  int tid = threadIdx.x;
  int c0 = ch * CPC;
  if (tid >= QCH) return;
  int q = sq * QCH + tid;
  const f4* xb = (const f4*)x + ((size_t)n * C_ + c0) * Q_ + q;
  f4 A = {0,0,0,0};
  #pragma unroll
  for (int c = 0; c < CPC; ++c) A += gc_w[c0 + c] * xb[(size_t)c * Q_];
  ((f4*)lpart)[((size_t)n * NCH + ch) * Q_ + q] = A;
}

// K2: fold 16 partials -> softmax over s per n. One block per n, float4.
__global__ void k_softmax(const float* __restrict__ lpart, float* __restrict__ attn) {
  int n = blockIdx.x, tid = threadIdx.x;
  __shared__ float red[4];
  const f4* lp = (const f4*)lpart + (size_t)n * NCH * Q_;
  f4 v[4];
  float m = -INFINITY;
  #pragma unroll
  for (int k = 0; k < 3; ++k) {
    int q = tid + k * 256;
    f4 acc = {0,0,0,0};
    #pragma unroll
    for (int ch = 0; ch < NCH; ++ch) acc += lp[(size_t)ch * Q_ + q];
    v[k] = acc;
    m = fmaxf(m, max4(acc));
  }
  if (tid < 16) {
    f4 acc = {0,0,0,0};
    #pragma unroll
    for (int ch = 0; ch < NCH; ++ch) acc += lp[(size_t)ch * Q_ + 768 + tid];
    v[3] = acc;
    m = fmaxf(m, max4(acc));
  } else {
    v[3] = f4{-INFINITY, -INFINITY, -INFINITY, -INFINITY};
  }
  float wm = wave_max(m);
  int lane = tid & 63, wid = tid >> 6;
  if (lane == 0) red[wid] = wm;
  __syncthreads();
  m = fmaxf(fmaxf(red[0], red[1]), fmaxf(red[2], red[3]));
  float z = 0.f;
  #pragma unroll
  for (int k = 0; k < 4; ++k) {
    v[k].x = expf(v[k].x - m); v[k].y = expf(v[k].y - m);
    v[k].z = expf(v[k].z - m); v[k].w = expf(v[k].w - m);
    z += v[k].x + v[k].y + v[k].z + v[k].w;   // exp(-inf)=0 for tail lanes
  }
  z = block_sum(z, red);
  float inv = 1.f / z;
  f4* ap = (f4*)attn + (size_t)n * Q_;
  #pragma unroll
  for (int k = 0; k < 3; ++k) ap[tid + k * 256] = v[k] * inv;
  if (tid < 16) ap[768 + tid] = v[3] * inv;
}

// K3: per (n,c): x_g, x_max, x_dct in one warm x pass. Block per (c,n) = 8192.
__global__ void k_stats(const float* __restrict__ x, const float* __restrict__ attn,
                        float* __restrict__ xg, float* __restrict__ xmax,
                        float* __restrict__ xdct) {
  int c = blockIdx.x, n = blockIdx.y, tid = threadIdx.x;
  __shared__ float bh[H_];
  __shared__ f4 bw4[14];
  __shared__ float red[3][4];
  int grp = c >> 6;
  int u = grp >> 1, vv = grp & 1;
  const float invs = 0.13363062f;   // 1/sqrt(56)
  const float sq2  = 1.41421356f;
  if (tid < H_) {
    float b = cosf((float)M_PI * u * (tid + 0.5f) / H_) * invs;
    bh[tid] = u ? b * sq2 : b;
  } else if (tid >= 64 && tid < 64 + 14) {
    int j = tid - 64;
    f4 b;
    #pragma unroll
    for (int e = 0; e < 4; ++e) {
      float t = cosf((float)M_PI * vv * (4 * j + e + 0.5f) / W_) * invs;
      ((float*)&b)[e] = vv ? t * sq2 : t;
    }
    bw4[j] = b;
  }
  __syncthreads();
  const f4* xp = (const f4*)(x + ((size_t)n * C_ + c) * S_);
  const f4* ap = (const f4*)(attn + (size_t)n * S_);
  float g = 0.f, d = 0.f, mx = -INFINITY;
  #pragma unroll
  for (int k = 0; k < 3; ++k) {
    int q = tid + k * 256;
    f4 xv = xp[q], av = ap[q];
    g += dot4(xv, av);
    mx = fmaxf(max4(xv), mx);
    int h = q / 14;
    d += bh[h] * dot4(xv, bw4[q - h * 14]);
  }
  if (tid < 16) {
    int q = 768 + tid;
    f4 xv = xp[q], av = ap[q];
    g += dot4(xv, av);
    mx = fmaxf(max4(xv), mx);
    int h = q / 14;
    d += bh[h] * dot4(xv, bw4[q - h * 14]);
  }
  float gs = wave_sum(g), ms = wave_max(mx), ds = wave_sum(d);
  int lane = tid & 63, wid = tid >> 6;
  if (lane == 0) { red[0][wid] = gs; red[1][wid] = ms; red[2][wid] = ds; }
  __syncthreads();
  if (tid == 0) {
    xg[n * C_ + c]   = red[0][0] + red[0][1] + red[0][2] + red[0][3];
    xmax[n * C_ + c] = fmaxf(fmaxf(red[1][0], red[1][1]), fmaxf(red[1][2], red[1][3]));
    xdct[n * C_ + c] = red[2][0] + red[2][1] + red[2][2] + red[2][3];
  }
}

// K4: per-n gate math, 1024 threads (16 waves/CU on 32 CUs).
// Matmul: 4 threads/row, thread j of row r reads contiguous 64B segments
// (16 line-requests/wave-instr), 16 independent f4 loads/thread, 2-shuffle
// 4-lane reduce. LN/scalar phases on tid<256.
__global__ __launch_bounds__(1024)
void k_gate(const float* __restrict__ xg, const float* __restrict__ xmax,
            const float* __restrict__ xdct,
            const float* __restrict__ lc_w, const float* __restrict__ lc_b,
            const float* __restrict__ lcln_g, const float* __restrict__ lcln_b,
            const float* __restrict__ tw_w, const float* __restrict__ tw_b,
            const float* __restrict__ twln_g, const float* __restrict__ twln_b,
            const float* __restrict__ wdct, const float* __restrict__ wmax,
            float* __restrict__ gate) {
  int n = blockIdx.x, tid = threadIdx.x;
  const bool active = tid < C_;
  __shared__ float xs[C_ + 2];
  __shared__ float att_s[C_];
  __shared__ float att2_s[C_];
  __shared__ float red[16];
  float t = 0.f;
  if (active) {
    int c = tid;
    float g  = xg[n * C_ + c];
    float sv = wmax[c] * xmax[n * C_ + c] + wdct[c] * xdct[n * C_ + c];
    xs[c + 1] = sv;
    if (c == 0) { xs[0] = 0.f; xs[C_ + 1] = 0.f; }
    t = g + sv;   // xl added after barrier
  }
  __syncthreads();
  if (active) {
    int c = tid;
    t += lc_w[0] * xs[c] + lc_w[1] * xs[c + 1] + lc_w[2] * xs[c + 2] + lc_b[0];
  }
  float mu  = block_sum16(active ? t : 0.f, red) * (1.f / C_);
  float dv  = t - mu;
  float var = block_sum16(active ? dv * dv : 0.f, red) * (1.f / C_);
  if (active) {
    int c = tid;
    att_s[c] = dv * rsqrtf(var + LN_EPS) * lcln_g[c] + lcln_b[c];
  }
  __syncthreads();
  // matmul: att2_s[row] = dot(tw_w[row], att_s); row = tid>>2, j = tid&3.
  {
    int row = tid >> 2, j = tid & 3;
    const f4* twr = (const f4*)tw_w + (size_t)row * 64;
    const f4* a4  = (const f4*)att_s;
    float acc = 0.f;
    #pragma unroll
    for (int k16 = 0; k16 < 16; ++k16)
      acc += dot4(twr[k16 * 4 + j], a4[k16 * 4 + j]);
    acc += __shfl_xor(acc, 1);
    acc += __shfl_xor(acc, 2);
    if (j == 0) att2_s[row] = acc;
  }
  __syncthreads();
  float a2 = active ? att2_s[tid] + tw_b[tid] : 0.f;
  float mu2  = block_sum16(active ? a2 : 0.f, red) * (1.f / C_);
  float d2   = a2 - mu2;
  float var2 = block_sum16(active ? d2 * d2 : 0.f, red) * (1.f / C_);
  if (active) {
    int c = tid;
    float z = d2 * rsqrtf(var2 + LN_EPS) * twln_g[c] + twln_b[c];
    gate[n * C_ + c] = 1.f / (1.f + expf(-z));
  }
}

// K5: out = x * gate[n,c], float4 grid-stride, NT stores.
__global__ void k_scale(const float* __restrict__ x, const float* __restrict__ gate,
                        float* __restrict__ out) {
  const f4* x4 = (const f4*)x;
  f4* o4 = (f4*)out;
  const int total = N_ * C_ * Q_;
  for (int i = blockIdx.x * blockDim.x + threadIdx.x; i < total;
       i += gridDim.x * blockDim.x) {
    int nc = i / Q_;
    float gv = gate[nc];
    f4 v = x4[i];
    v *= gv;
    __builtin_nontemporal_store(v, &o4[i]);
  }
}

extern "C" void kernel_launch(void* const* d_in, const int* in_sizes, int n_in,
                              void* d_out, int out_size, void* d_ws, size_t ws_size,
                              hipStream_t stream) {
  const float* x      = (const float*)d_in[0];
  const float* gc_w   = (const float*)d_in[1];
  // d_in[2] = gc_b: softmax shift-invariant, unused
  const float* lc_w   = (const float*)d_in[3];
  const float* lc_b   = (const float*)d_in[4];
  const float* lcln_g = (const float*)d_in[5];
  const float* lcln_b = (const float*)d_in[6];
  const float* tw_w   = (const float*)d_in[7];
  const float* tw_b   = (const float*)d_in[8];
  const float* twln_g = (const float*)d_in[9];
  const float* twln_b = (const float*)d_in[10];
  const float* wdct   = (const float*)d_in[11];
  const float* wmax   = (const float*)d_in[12];
  float* out = (float*)d_out;

  float* ws    = (float*)d_ws;
  float* lpart = ws;                                   // NCH*N*S
  float* attn  = lpart + (size_t)NCH * N_ * S_;        // N*S
  float* xg    = attn + (size_t)N_ * S_;               // N*C
  float* xmax_ = xg + N_ * C_;
  float* xdct_ = xmax_ + N_ * C_;
  float* gate  = xdct_ + N_ * C_;

  hipLaunchKernelGGL(k_logits, dim3(NCH, N_, SQ), dim3(256), 0, stream, x, gc_w, lpart);
  hipLaunchKernelGGL(k_softmax, dim3(N_), dim3(256), 0, stream, lpart, attn);
  hipLaunchKernelGGL(k_stats, dim3(C_, N_), dim3(256), 0, stream, x, attn, xg, xmax_, xdct_);
  hipLaunchKernelGGL(k_gate, dim3(N_), dim3(1024), 0, stream,
                     xg, xmax_, xdct_, lc_w, lc_b, lcln_g, lcln_b,
                     tw_w, tw_b, twln_g, twln_b, wdct, wmax, gate);
  hipLaunchKernelGGL(k_scale, dim3(2048), dim3(256), 0, stream, x, gate, out);
}